// Round 11
// baseline (232.040 us; speedup 1.0000x reference)
//
#include <hip/hip_runtime.h>
#include <hip/hip_bf16.h>

// ---------- helpers ----------

typedef __attribute__((ext_vector_type(8))) short bf16x8;
typedef __attribute__((ext_vector_type(4))) float f32x4;

#define AS_G(p) ((__attribute__((address_space(1))) void*)(p))
#define AS_L(p) ((__attribute__((address_space(3))) void*)(p))

__device__ __forceinline__ unsigned short f2bf(float f) {
  unsigned int u = __float_as_uint(f);
  unsigned int lsb = (u >> 16) & 1u;
  u += 0x7fffu + lsb;
  return (unsigned short)(u >> 16);
}

#define WAITV(n) asm volatile("s_waitcnt vmcnt(" #n ")" ::: "memory")
#define BAR() do { asm volatile("" ::: "memory");                             \
    __builtin_amdgcn_s_barrier();                                             \
    asm volatile("" ::: "memory"); } while (0)

// ---------- 128x128 2-region NT GEMM, counted vmcnt, 2 BLOCKS PER CU ----------
// R8 (validated: MfmaUtil 31->35.4): 128x128 tile, 256 thr = 4 waves
// (2M x 2N, per-wave 64x64), LDS 2 buf x 32KB = 64KB -> TWO blocks/CU with
// independent barrier groups; block A's LDS bursts overlap block B's MFMA
// bursts (m114). ~LDS-port-bound: per tile-pair observed 2990 cyc vs port
// floor ~2048 + MFMA 1241.
//
// R9 post-mortem: XCD-chunked swizzle is PER-DISPATCH:
//  - proj: REGRESSED 59.8->65.4us, FETCH 76.5->118MB. Cause: a proj chunk
//    (192 blocks = 8y x all 24x) spans the full WT -> WT (6MB) replicated
//    into all 8 L2s (+48MB ~= measured +42MB). SWZ=0 (R8 plain x-fastest).
//  - QK/PV (+prep fusion): gained ~24us. Chunk = 8y x full-x within one
//    batch ~= 6MB working set, beats round-robin. SWZ=1 kept.
// (R10 bench was an infrastructure failure -- container acquisition; this
// source is resubmitted unchanged.)
//
// A[m,k] lda, B[n,k] ldb, bf16, K-contiguous. BK=64, acc[4][4]/wave.
// Swizzle (0 SQ_LDS_BANK_CONFLICT all rounds): LDS row = 8 chunks of 8
// elems (16B); slot s of row r holds k-chunk s ^ (r&7); staging pre-swizzles
// the GLOBAL source so the LDS dest stays linear (global_load_lds req).
//
// 2-region K-tile (R5/R8 audit): R1 = {all A frag-reads (both ks) + B jh0
// reads; carry-stage B(t+1) -> OTHER buf; bar; MFMA cols 0-1; bar}. R2 =
// {B jh1 reads; lead-stage A(t+2) -> THIS buf; bar; MFMA cols 2-3;
// vmcnt(4); bar}. WAR: A rows of buf(t) die after R1 (lead is barrier-
// ordered); B jh0/jh1 rows die after R1/R2; carry targets buf(t+1) whose
// tenant t-1 was fully read by end of tile t-1. RAW: end of tile t-1's
// vmcnt(4) keeps only lead A(t+1); drains everything older -> buf(t)
// complete (loads finish oldest-first, m135). Never drains to 0 in steady
// state (m218). Prologue stages t0+t1 (16 loads), vmcnt(8). Per-element
// accumulation order identical to R5/R8/R9 -> bit-identical output.
//
// EPI=1: QK: P' = bf16(exp(acc*scale)) (unnormalized softmax numerator;
//        |acc*scale| small by construction) + fp32 atomic row-sum to rsum.
// EPI=2: proj split: col seg 0 -> qb (+bq), seg 1 -> kb (+bk), seg 2 -> vt
//        TRANSPOSED (+bv) as ushort4.
// EPI=3: PV: out fp32 = acc / rsum[row].

#define BUFE 16384  // elems per LDS buffer: A 8192 + B 8192 (32 KB)

// stage one 32-row block (1 global_load_lds per thread, 256thr x 16B = 4KB)
#define S32A(ktk, rb, bofs)                                                   \
  __builtin_amdgcn_global_load_lds(                                           \
      AS_G(A + (size_t)(rowBase + (rb) * 32 + r0) * lda + (ktk) + goff),      \
      AS_L(lds + (bofs) + (rb) * 2048 + t * 8), 16, 0, 0)

#define S32B(ktk, rb, bofs)                                                   \
  __builtin_amdgcn_global_load_lds(                                           \
      AS_G(B + (size_t)(colBase + (rb) * 32 + r0) * ldb + (ktk) + goff),      \
      AS_L(lds + (bofs) + 8192 + (rb) * 2048 + t * 8), 16, 0, 0)

// all A frag-reads for this wave (both K-halves): 8 x ds_read_b128
#define LDA4(bofs) do { _Pragma("unroll")                                     \
    for (int ks_ = 0; ks_ < 2; ks_++) { _Pragma("unroll")                     \
      for (int ii = 0; ii < 4; ii++) {                                        \
        int row_ = wrow + ii * 16 + r16;                                      \
        int slot_ = (ks_ * 4 + q) ^ (r16 & 7);                                \
        af[ks_][ii] = *(const bf16x8*)(lds + (bofs) + row_ * 64 + slot_ * 8); \
      } } } while (0)

// B frag-reads for col-half jh (both K-halves): 4 x ds_read_b128
#define LDB(jh, bofs) do { _Pragma("unroll")                                  \
    for (int ks_ = 0; ks_ < 2; ks_++) { _Pragma("unroll")                     \
      for (int jj = 0; jj < 2; jj++) {                                        \
        int row_ = wcol + ((jh) * 2 + jj) * 16 + r16;                         \
        int slot_ = (ks_ * 4 + q) ^ (r16 & 7);                                \
        bfr[ks_][(jh) * 2 + jj] =                                             \
            *(const bf16x8*)(lds + (bofs) + 8192 + row_ * 64 + slot_ * 8);    \
      } } } while (0)

#define MMQ(j0, j1) do { __builtin_amdgcn_s_setprio(1); _Pragma("unroll")     \
    for (int ks_ = 0; ks_ < 2; ks_++) { _Pragma("unroll")                     \
      for (int ii = 0; ii < 4; ii++) { _Pragma("unroll")                      \
        for (int jj = (j0); jj <= (j1); jj++)                                 \
          acc[ii][jj] = __builtin_amdgcn_mfma_f32_16x16x32_bf16(              \
              af[ks_][ii], bfr[ks_][jj], acc[ii][jj], 0, 0, 0);               \
      } }                                                                     \
    __builtin_amdgcn_s_setprio(0); } while (0)

#define TILE(ktc, bofs, obofs) do {                                           \
    /* R1: all-A + B jh0 reads; carry B(t+1) -> other buf */                  \
    LDA4(bofs); LDB(0, bofs);                                                 \
    if ((ktc) && (ktc) + 64 < K) {                                            \
      S32B((ktc) + 64, 0, obofs); S32B((ktc) + 64, 1, obofs);                 \
      S32B((ktc) + 64, 2, obofs); S32B((ktc) + 64, 3, obofs);                 \
    }                                                                         \
    BAR(); MMQ(0, 1); BAR();                                                  \
    /* R2: B jh1 reads; lead A(t+2) -> this buf; counted wait */              \
    LDB(1, bofs);                                                             \
    if ((ktc) + 128 < K) {                                                    \
      S32A((ktc) + 128, 0, bofs); S32A((ktc) + 128, 1, bofs);                 \
      S32A((ktc) + 128, 2, bofs); S32A((ktc) + 128, 3, bofs);                 \
    }                                                                         \
    BAR(); MMQ(2, 3);                                                         \
    if ((ktc) + 128 < K) { WAITV(4); } else { WAITV(0); }                     \
    BAR(); } while (0)

template <int EPI, int SWZ>
__global__ __launch_bounds__(256, 2) void gemm_db(
    const unsigned short* __restrict__ A, const unsigned short* __restrict__ B,
    float* __restrict__ Cf, long long sA, long long sB, long long sC,
    int K, int lda, int ldb, int ldc,
    unsigned short* __restrict__ u0, unsigned short* __restrict__ u1,
    unsigned short* __restrict__ u2,
    const float* __restrict__ f0, const float* __restrict__ f1,
    const float* __restrict__ f2,
    float* __restrict__ rsum, float scale, int gx, int gy)
{
  __shared__ unsigned short lds[2 * BUFE];  // 64 KiB -> 2 blocks/CU

  const int t = threadIdx.x;

  // Tile-order decode (1D launch). SWZ=1: XCD-chunked bijective swizzle --
  // XCD c (= launch id % 8) gets the contiguous run [c*cpx,(c+1)*cpx) of the
  // x-fastest order (QK/PV win). SWZ=0: plain x-fastest (proj: chunking
  // replicates the fully-shared WT into all 8 L2s, +42MB FETCH -- R9).
  int swz;
  if constexpr (SWZ) {
    const int cpx = gridDim.x >> 3;
    swz = (blockIdx.x & 7) * cpx + (blockIdx.x >> 3);
  } else {
    swz = blockIdx.x;
  }
  const int bx = swz % gx;
  const int byz = swz / gx;
  const int by = byz % gy;
  const int bz = byz / gy;

  const int rowBase = by * 128;
  const int colBase = bx * 128;
  A += (long long)bz * sA;
  B += (long long)bz * sB;

  const int l = t & 63;
  const int w = t >> 6;              // 0..3
  const int wrow = (w >> 1) * 64;    // 2 M-waves
  const int wcol = (w & 1) * 64;     // 2 N-waves
  const int q = l >> 4;
  const int r16 = l & 15;

  // staging geometry: thread t covers row r0 = t>>3 (of a 32-row block),
  // slot t&7, global k-chunk = (t&7)^(r0&7) (pre-swizzled source).
  const int r0 = t >> 3;                        // 0..31
  const int goff = ((t & 7) ^ (r0 & 7)) << 3;

  f32x4 acc[4][4] = {};
  bf16x8 af[2][4], bfr[2][4];

  // prologue: t0 -> buf0 (8 loads), t1 -> buf1 (8 loads); drain t0 only.
  S32A(0, 0, 0); S32A(0, 1, 0); S32A(0, 2, 0); S32A(0, 3, 0);
  S32B(0, 0, 0); S32B(0, 1, 0); S32B(0, 2, 0); S32B(0, 3, 0);
  S32A(64, 0, BUFE); S32A(64, 1, BUFE); S32A(64, 2, BUFE); S32A(64, 3, BUFE);
  S32B(64, 0, BUFE); S32B(64, 1, BUFE); S32B(64, 2, BUFE); S32B(64, 3, BUFE);
  WAITV(8);
  BAR();

  for (int kt = 0; kt < K; kt += 128) {   // K is a multiple of 128
    TILE(kt, 0, BUFE);
    TILE(kt + 64, BUFE, 0);
  }

  // epilogues: C frag layout row=(lane>>4)*4+r, col=lane&15 (m89/m91)
  if (EPI == 1) {
    unsigned short* p16 = u0 + (long long)bz * sC;
    float* rs = rsum + (long long)bz * 2048;
#pragma unroll
    for (int i = 0; i < 4; i++) {
#pragma unroll
      for (int r = 0; r < 4; r++) {
        int row = rowBase + wrow + i * 16 + q * 4 + r;
        float rowpart = 0.f;
#pragma unroll
        for (int j = 0; j < 4; j++) {
          int col = colBase + wcol + j * 16 + r16;
          float e = __expf(acc[i][j][r] * scale);
          p16[(size_t)row * ldc + col] = f2bf(e);
          rowpart += e;
        }
#pragma unroll
        for (int m = 1; m < 16; m <<= 1) rowpart += __shfl_xor(rowpart, m);
        if (r16 == 0) atomicAdd(rs + row, rowpart);
      }
    }
  } else if (EPI == 2) {
    const int seg = colBase >> 10;  // block-uniform (128-tile never straddles)
    if (seg < 2) {
      unsigned short* dst = seg ? u1 : u0;
      const float* bias = seg ? f1 : f0;
      const int cb = colBase & 1023;
#pragma unroll
      for (int i = 0; i < 4; i++) {
#pragma unroll
        for (int r = 0; r < 4; r++) {
          int row = rowBase + wrow + i * 16 + q * 4 + r;
#pragma unroll
          for (int j = 0; j < 4; j++) {
            int col = cb + wcol + j * 16 + r16;
            dst[(size_t)row * 1024 + col] = f2bf(acc[i][j][r] + bias[col]);
          }
        }
      }
    } else {
      const int ob = colBase - 2048;
#pragma unroll
      for (int i = 0; i < 4; i++) {
        int posBase = rowBase + wrow + i * 16 + q * 4;
        int b = posBase >> 11;
        int pos = posBase & 2047;
#pragma unroll
        for (int j = 0; j < 4; j++) {
          int o = ob + wcol + j * 16 + r16;
          float bias = f2[o];
          ushort4 pk;
          pk.x = f2bf(acc[i][j][0] + bias);
          pk.y = f2bf(acc[i][j][1] + bias);
          pk.z = f2bf(acc[i][j][2] + bias);
          pk.w = f2bf(acc[i][j][3] + bias);
          *(ushort4*)(u2 + ((size_t)((b << 10) + o) * 2048 + pos)) = pk;
        }
      }
    }
  } else {  // EPI == 3
    float* C = Cf + (long long)bz * sC;
    const float* rs = rsum + (long long)bz * 2048;
#pragma unroll
    for (int i = 0; i < 4; i++) {
#pragma unroll
      for (int r = 0; r < 4; r++) {
        int row = rowBase + wrow + i * 16 + q * 4 + r;
        float inv = 1.0f / rs[row];
#pragma unroll
        for (int j = 0; j < 4; j++) {
          int col = colBase + wcol + j * 16 + r16;
          C[(size_t)row * ldc + col] = acc[i][j][r] * inv;
        }
      }
    }
  }
}

// ---------- fused prep: cast x->bf16 + rsum zero + W transpose (one launch) ----------
// blocks [0, 8192): cast 4 floats each (8192*256*4 = 8M = M*D elems) +
//                   zero rsum float4s.
// blocks [8192, 11264): wtrans, b-8192 -> (z, by, bx) with 32x8 tile logic.

__global__ __launch_bounds__(256) void prep(
    const float* __restrict__ in, unsigned short* __restrict__ out,
    float* __restrict__ rzero, int nz4,
    const float* __restrict__ Wq, const float* __restrict__ Wk,
    const float* __restrict__ Wv, unsigned short* __restrict__ WT)
{
  __shared__ float tile[32][33];
  const int bid = blockIdx.x;
  const int t = threadIdx.x;
  if (bid < 8192) {
    int i = bid * 256 + t;
    if (i < nz4) ((float4*)rzero)[i] = make_float4(0.f, 0.f, 0.f, 0.f);
    float4 v = ((const float4*)in)[i];
    ushort4 o;
    o.x = f2bf(v.x); o.y = f2bf(v.y); o.z = f2bf(v.z); o.w = f2bf(v.w);
    ((ushort4*)out)[i] = o;
  } else {
    const int b = bid - 8192;
    const int z = b >> 10;            // 0..2
    const int by = (b & 1023) >> 5;   // 0..31 (d block)
    const int bx = b & 31;            // 0..31 (h block)
    const float* src = z == 0 ? Wq : (z == 1 ? Wk : Wv);
    unsigned short* dst = WT + (size_t)z * 1024 * 1024;
    const int bc = bx * 32;  // h
    const int br = by * 32;  // d
    const int tx = t & 31;
    const int ty = t >> 5;   // 0..7
#pragma unroll
    for (int i = 0; i < 4; i++)
      tile[ty + i * 8][tx] = src[(size_t)(br + ty + i * 8) * 1024 + bc + tx];
    __syncthreads();
#pragma unroll
    for (int i = 0; i < 4; i++)
      dst[(size_t)(bc + ty + i * 8) * 1024 + br + tx] = f2bf(tile[tx][ty + i * 8]);
  }
}

// ---------- driver ----------

extern "C" void kernel_launch(void* const* d_in, const int* in_sizes, int n_in,
                              void* d_out, int out_size, void* d_ws, size_t ws_size,
                              hipStream_t stream) {
  (void)in_sizes; (void)n_in; (void)out_size;

  const float* x  = (const float*)d_in[0];
  const float* Wq = (const float*)d_in[1];
  const float* bq = (const float*)d_in[2];
  const float* Wk = (const float*)d_in[3];
  const float* bk = (const float*)d_in[4];
  const float* Wv = (const float*)d_in[5];
  const float* bv = (const float*)d_in[6];
  float* out = (float*)d_out;

  const int Nb = 4, L = 2048, D = 1024, H = 1024, O = 1024;
  const int M = Nb * L;      // 8192
  const int NQKV = 3 * H;    // 3072

  char* ws = (char*)d_ws;
  size_t off = 0;
  unsigned short* xb = (unsigned short*)(ws + off); off += (size_t)M * D * 2;
  unsigned short* qb = (unsigned short*)(ws + off); off += (size_t)M * H * 2;
  unsigned short* kb = (unsigned short*)(ws + off); off += (size_t)M * H * 2;
  unsigned short* vt = (unsigned short*)(ws + off); off += (size_t)M * O * 2;
  unsigned short* WT = (unsigned short*)(ws + off); off += (size_t)NQKV * D * 2;
  unsigned short* P  = (unsigned short*)(ws + off); off += (size_t)Nb * L * L * 2;
  float* rsum = (float*)(ws + off); off += (size_t)Nb * L * 4;
  if (ws_size < off) return;

  dim3 blk256(256);

  // fused prep: x -> bf16, rsum zero (ws poisoned every call), W transposes
  prep<<<dim3(8192 + 3072), blk256, 0, stream>>>(
      x, xb, rsum, Nb * L / 4, Wq, Wk, Wv, WT);

  // fused projections: q -> qb, k -> kb, v -> vt (transposed), + biases
  // 1536 blocks = 3.0 exact dual-rounds; SWZ=0 (R9: chunking replicated WT)
  gemm_db<2, 0><<<dim3(1536), blk256, 0, stream>>>(
      xb, WT, nullptr, 0, 0, 0, D, D, D, 0,
      qb, kb, vt, bq, bk, bv, nullptr, 0.f, 24, 64);

  // QK + exp + row-sum atomics: P'[b] = exp(q k^T * scale)
  // 1024 blocks = 2.0 exact dual-rounds; SWZ=1 (R9 win)
  gemm_db<1, 1><<<dim3(1024), blk256, 0, stream>>>(
      qb, kb, nullptr, (long long)L * H, (long long)L * H, (long long)L * L,
      H, H, H, L,
      P, nullptr, nullptr, nullptr, nullptr, nullptr,
      rsum, 0.022097086912079608f /* 1/sqrt(2048) */, 16, 16);

  // out[b] = (P'[b] @ vt[b]^T) / rsum
  // 512 blocks = 1.0 exact dual-round; SWZ=1 (R9 win)
  gemm_db<3, 1><<<dim3(512), blk256, 0, stream>>>(
      P, vt, out, (long long)L * L, (long long)O * L, (long long)L * O,
      L, L, L, O,
      nullptr, nullptr, nullptr, nullptr, nullptr, nullptr,
      rsum, 0.f, 8, 16);
}